// Round 3
// baseline (311.810 us; speedup 1.0000x reference)
//
#include <hip/hip_runtime.h>
#include <hip/hip_bf16.h>
#include <stdint.h>

#define N_NODES 150000
#define C_IN 32
#define C_OUT 64
#define K_TAPS 27
#define PF 3
#define NSLOTS 32

#define TRANS_BLOCKS 2344           // 2344*64 = 150016 nodes (incl. pad row)
#define WPREP_BLOCKS 216            // 216*256 >= 64*32*27 = 55296
#define CONV_BLOCKS 1172            // 1172*128 = 150016

typedef __attribute__((ext_vector_type(8))) __bf16 bf16x8;
typedef __attribute__((ext_vector_type(4))) float f32x4;

__device__ __forceinline__ ushort f2bf(float f) {
    union { float f; uint32_t u; } v; v.f = f;
    uint32_t u = v.u;
    return (ushort)((u + 0x7FFFu + ((u >> 16) & 1u)) >> 16);
}

// ---------------------------------------------------------------------------
// Kernel 1 (fused prep): blocks [0,2344) transpose x (32x150000 fp32) ->
// xT (150001 x 32 bf16, zero pad row). Blocks [2344,2560) repack W and zero stats.
// ---------------------------------------------------------------------------
__global__ __launch_bounds__(256) void k_prep(const float* __restrict__ x,
                                              ushort* __restrict__ xT,
                                              const float* __restrict__ W,
                                              ushort* __restrict__ A_frag,
                                              float* __restrict__ stats) {
    int t = threadIdx.x;
    int b = blockIdx.x;
    if (b < TRANS_BLOCKS) {
        __shared__ float tile[32][65];
        int nb = b * 64;
        int nl = t & 63, i4 = t >> 6;
#pragma unroll
        for (int rep = 0; rep < 8; ++rep) {
            int i = rep * 4 + i4;
            int n = nb + nl;
            tile[i][nl] = (n < N_NODES) ? x[(size_t)i * N_NODES + n] : 0.0f;
        }
        __syncthreads();
        int nr = t >> 2, c0 = (t & 3) * 8;
        int n = nb + nr;
        if (n <= N_NODES) {
            uint32_t w[4];
#pragma unroll
            for (int j = 0; j < 4; ++j) {
                ushort lo = f2bf(tile[c0 + 2 * j][nr]);
                ushort hi = f2bf(tile[c0 + 2 * j + 1][nr]);
                w[j] = (uint32_t)lo | ((uint32_t)hi << 16);
            }
            *reinterpret_cast<uint4*>(xT + (size_t)n * 32 + c0) =
                make_uint4(w[0], w[1], w[2], w[3]);
        }
    } else {
        // W repack: A_frag[(k*4+m)*512 + lane*8 + j] = W[m*16+(lane&15)][(lane>>4)*8+j][k]
        int tid = (b - TRANS_BLOCKS) * 256 + t;
        if (tid < NSLOTS * 128 + 128) stats[tid] = 0.0f;
        if (tid < C_OUT * C_IN * K_TAPS) {
            int j = tid & 7;
            int ln = (tid >> 3) & 63;
            int km = tid >> 9;
            int m = km & 3;
            int k = km >> 2;
            int o = m * 16 + (ln & 15);
            int i = (ln >> 4) * 8 + j;
            A_frag[tid] = f2bf(W[o * (C_IN * K_TAPS) + i * K_TAPS + k]);
        }
    }
}

// ---------------------------------------------------------------------------
// Kernel 2: gather-GEMM. 4 waves/block, 32 nodes/wave (128/block), full C_OUT.
// Depth-3 register pipeline on A (coalesced) and B (gather) fragments.
// ---------------------------------------------------------------------------
__global__ __launch_bounds__(256, 6) void k_conv(const ushort* __restrict__ xT,
                                                 const ushort* __restrict__ A_frag,
                                                 const int* __restrict__ neigh,
                                                 float* __restrict__ y,
                                                 float* __restrict__ stats) {
    __shared__ int soff[128 * K_TAPS];  // pre-scaled byte offsets into xT
    int t = threadIdx.x;
    int nblk = blockIdx.x * 128;
    for (int j = t; j < 128 * K_TAPS; j += 256) {
        int ng = nblk + j / K_TAPS;
        int idx = (ng < N_NODES) ? neigh[(size_t)nblk * K_TAPS + j] : N_NODES;
        soff[j] = idx << 6;  // 64 B per xT row
    }
    __syncthreads();

    int wid = t >> 6, lane = t & 63;
    int l15 = lane & 15, quad = lane >> 4;
    int qoff = quad << 4;
    int nb = nblk + wid * 32;

    const char* xTb = (const char*)xT;
    const char* aB = (const char*)A_frag + (size_t)lane * 16;
    const int* so = soff + wid * 32 * K_TAPS;

    f32x4 acc[4][2];
#pragma unroll
    for (int m = 0; m < 4; ++m)
#pragma unroll
        for (int g = 0; g < 2; ++g) acc[m][g] = (f32x4){0.f, 0.f, 0.f, 0.f};

    bf16x8 bb[PF][2], aa[PF][4];
#pragma unroll
    for (int s = 0; s < PF; ++s) {
#pragma unroll
        for (int g = 0; g < 2; ++g)
            bb[s][g] = *reinterpret_cast<const bf16x8*>(
                xTb + (uint32_t)so[(g * 16 + l15) * K_TAPS + s] + qoff);
#pragma unroll
        for (int m = 0; m < 4; ++m)
            aa[s][m] = *reinterpret_cast<const bf16x8*>(aB + ((size_t)(s * 4 + m) << 10));
    }

#pragma unroll 3
    for (int k = 0; k < K_TAPS; ++k) {
        int cur = k % PF;
#pragma unroll
        for (int m = 0; m < 4; ++m)
#pragma unroll
            for (int g = 0; g < 2; ++g)
                acc[m][g] = __builtin_amdgcn_mfma_f32_16x16x32_bf16(
                    aa[cur][m], bb[cur][g], acc[m][g], 0, 0, 0);
        if (k < K_TAPS - PF) {
            int kn = k + PF;
#pragma unroll
            for (int g = 0; g < 2; ++g)
                bb[cur][g] = *reinterpret_cast<const bf16x8*>(
                    xTb + (uint32_t)so[(g * 16 + l15) * K_TAPS + kn] + qoff);
#pragma unroll
            for (int m = 0; m < 4; ++m)
                aa[cur][m] = *reinterpret_cast<const bf16x8*>(
                    aB + ((size_t)(kn * 4 + m) << 10));
        }
    }

    // store y tile (C/D: col=l15 -> node, row=quad*4+r -> channel)
#pragma unroll
    for (int m = 0; m < 4; ++m) {
        int obase = m * 16 + quad * 4;
#pragma unroll
        for (int g = 0; g < 2; ++g) {
            int n = nb + g * 16 + l15;
            if (n < N_NODES) {
#pragma unroll
                for (int r = 0; r < 4; ++r)
                    y[(size_t)(obase + r) * N_NODES + n] = acc[m][g][r];
            }
        }
    }

    // per-channel partial sums, striped over NSLOTS buffers
    int slot = blockIdx.x & (NSLOTS - 1);
#pragma unroll
    for (int m = 0; m < 4; ++m) {
#pragma unroll
        for (int r = 0; r < 4; ++r) {
            float s = 0.f, sq = 0.f;
#pragma unroll
            for (int g = 0; g < 2; ++g) {
                float v = acc[m][g][r];
                s += v;
                sq += v * v;
            }
#pragma unroll
            for (int d = 1; d < 16; d <<= 1) {
                s += __shfl_xor(s, d);
                sq += __shfl_xor(sq, d);
            }
            if (l15 == 0) {
                int o = m * 16 + quad * 4 + r;
                atomicAdd(&stats[slot * 128 + o], s);
                atomicAdd(&stats[slot * 128 + 64 + o], sq);
            }
        }
    }
}

// ---------------------------------------------------------------------------
// Kernel 3: finalize stats (per block, cheap) + in-place BN + ReLU on y.
// Grid: (37, 64); each block: 1024 float4 = 4096 floats of one channel.
// ---------------------------------------------------------------------------
__global__ __launch_bounds__(256) void k_bn_relu(float* __restrict__ y,
                                                 const float* __restrict__ stats,
                                                 const float* __restrict__ gamma,
                                                 const float* __restrict__ beta) {
    __shared__ float s_sc, s_sh;
    int t = threadIdx.x;
    int o = blockIdx.y;
    if (t < 32) {
        float s = stats[t * 128 + o];
        float sq = stats[t * 128 + 64 + o];
#pragma unroll
        for (int d = 1; d < 32; d <<= 1) {
            s += __shfl_xor(s, d);
            sq += __shfl_xor(sq, d);
        }
        if (t == 0) {
            const float invN = 1.0f / (float)N_NODES;
            float mean = s * invN;
            float var = sq * invN - mean * mean;
            float rstd = rsqrtf(var + 1e-3f);
            float sc = gamma[o] * rstd;
            s_sc = sc;
            s_sh = beta[o] - mean * sc;
        }
    }
    __syncthreads();
    float sc = s_sc, sh = s_sh;
    float4* row = reinterpret_cast<float4*>(y + (size_t)o * N_NODES);
    int base = blockIdx.x * 1024 + t;
#pragma unroll
    for (int it = 0; it < 4; ++it) {
        int i = base + it * 256;
        if (i < N_NODES / 4) {
            float4 v = row[i];
            v.x = fmaxf(fmaf(v.x, sc, sh), 0.f);
            v.y = fmaxf(fmaf(v.y, sc, sh), 0.f);
            v.z = fmaxf(fmaf(v.z, sc, sh), 0.f);
            v.w = fmaxf(fmaf(v.w, sc, sh), 0.f);
            row[i] = v;
        }
    }
}

extern "C" void kernel_launch(void* const* d_in, const int* in_sizes, int n_in,
                              void* d_out, int out_size, void* d_ws, size_t ws_size,
                              hipStream_t stream) {
    const float* data_in = (const float*)d_in[0];
    const int* neigh = (const int*)d_in[1];
    const float* W = (const float*)d_in[2];
    const float* gamma = (const float*)d_in[3];
    const float* beta = (const float*)d_in[4];
    float* out = (float*)d_out;

    char* ws = (char*)d_ws;
    ushort* xT = (ushort*)ws;                     // 150016*32*2 = 9,601,024 B
    ushort* A_frag = (ushort*)(ws + 9601024);     // 64*864*2    =   110,592 B
    float* stats = (float*)(ws + 9711616);        // 32*128 partials (+pad)

    k_prep<<<TRANS_BLOCKS + WPREP_BLOCKS, 256, 0, stream>>>(data_in, xT, W, A_frag,
                                                            stats);
    k_conv<<<CONV_BLOCKS, 256, 0, stream>>>(xT, A_frag, neigh, out, stats);
    k_bn_relu<<<dim3((N_NODES / 4 + 1023) / 1024, C_OUT), 256, 0, stream>>>(
        out, stats, gamma, beta);
}

// Round 4
// 179.209 us; speedup vs baseline: 1.7399x; 1.7399x over previous
//
#include <hip/hip_runtime.h>
#include <hip/hip_bf16.h>
#include <stdint.h>

#define N_NODES 150000
#define C_IN 32
#define C_OUT 64
#define K_TAPS 27
#define PF 3
#define NSLOTS 32

#define TRANS_BLOCKS 2344           // 2344*64 = 150016 nodes (incl. pad row)
#define WPREP_BLOCKS 216            // 216*256 >= 64*32*27 = 55296
#define CONV_BLOCKS 2344            // 2344*64 = 150016 nodes, 2 waves/block

typedef __attribute__((ext_vector_type(8))) __bf16 bf16x8;
typedef __attribute__((ext_vector_type(4))) float f32x4;

__device__ __forceinline__ ushort f2bf(float f) {
    union { float f; uint32_t u; } v; v.f = f;
    uint32_t u = v.u;
    return (ushort)((u + 0x7FFFu + ((u >> 16) & 1u)) >> 16);
}

// ---------------------------------------------------------------------------
// Kernel 1 (fused prep): blocks [0,2344) transpose x (32x150000 fp32) ->
// xT (150001 x 32 bf16, zero pad row). Blocks [2344,2560) repack W and zero stats.
// ---------------------------------------------------------------------------
__global__ __launch_bounds__(256) void k_prep(const float* __restrict__ x,
                                              ushort* __restrict__ xT,
                                              const float* __restrict__ W,
                                              ushort* __restrict__ A_frag,
                                              float* __restrict__ stats) {
    int t = threadIdx.x;
    int b = blockIdx.x;
    if (b < TRANS_BLOCKS) {
        __shared__ float tile[32][65];
        int nb = b * 64;
        int nl = t & 63, i4 = t >> 6;
#pragma unroll
        for (int rep = 0; rep < 8; ++rep) {
            int i = rep * 4 + i4;
            int n = nb + nl;
            tile[i][nl] = (n < N_NODES) ? x[(size_t)i * N_NODES + n] : 0.0f;
        }
        __syncthreads();
        int nr = t >> 2, c0 = (t & 3) * 8;
        int n = nb + nr;
        if (n <= N_NODES) {
            uint32_t w[4];
#pragma unroll
            for (int j = 0; j < 4; ++j) {
                ushort lo = f2bf(tile[c0 + 2 * j][nr]);
                ushort hi = f2bf(tile[c0 + 2 * j + 1][nr]);
                w[j] = (uint32_t)lo | ((uint32_t)hi << 16);
            }
            *reinterpret_cast<uint4*>(xT + (size_t)n * 32 + c0) =
                make_uint4(w[0], w[1], w[2], w[3]);
        }
    } else {
        // W repack: A_frag[(k*4+m)*512 + lane*8 + j] = W[m*16+(lane&15)][(lane>>4)*8+j][k]
        int tid = (b - TRANS_BLOCKS) * 256 + t;
        if (tid < NSLOTS * 128 + 128) stats[tid] = 0.0f;
        if (tid < C_OUT * C_IN * K_TAPS) {
            int j = tid & 7;
            int ln = (tid >> 3) & 63;
            int km = tid >> 9;
            int m = km & 3;
            int k = km >> 2;
            int o = m * 16 + (ln & 15);
            int i = (ln >> 4) * 8 + j;
            A_frag[tid] = f2bf(W[o * (C_IN * K_TAPS) + i * K_TAPS + k]);
        }
    }
}

// ---------------------------------------------------------------------------
// Kernel 2: gather-GEMM. 2 waves/block (128 thr), 32 nodes/wave, full C_OUT=64.
// Depth-3 register pipeline on A (coalesced) and B (gather) fragments.
// launch_bounds(128,4): VGPR cap 128 >> measured 60 — no spill (round-3 lesson).
// ---------------------------------------------------------------------------
__global__ __launch_bounds__(128, 4) void k_conv(const ushort* __restrict__ xT,
                                                 const ushort* __restrict__ A_frag,
                                                 const int* __restrict__ neigh,
                                                 float* __restrict__ y,
                                                 float* __restrict__ stats) {
    __shared__ int soff[64 * K_TAPS];  // pre-scaled byte offsets into xT
    int t = threadIdx.x;
    int nblk = blockIdx.x * 64;
    for (int j = t; j < 64 * K_TAPS; j += 128) {
        int ng = nblk + j / K_TAPS;
        int idx = (ng < N_NODES) ? neigh[(size_t)nblk * K_TAPS + j] : N_NODES;
        soff[j] = idx << 6;  // 64 B per xT row
    }
    __syncthreads();

    int wid = t >> 6, lane = t & 63;
    int l15 = lane & 15, quad = lane >> 4;
    int qoff = quad << 4;
    int nb = nblk + wid * 32;

    const char* xTb = (const char*)xT;
    const char* aB = (const char*)A_frag + (size_t)lane * 16;
    const int* so = soff + wid * 32 * K_TAPS;

    f32x4 acc[4][2];
#pragma unroll
    for (int m = 0; m < 4; ++m)
#pragma unroll
        for (int g = 0; g < 2; ++g) acc[m][g] = (f32x4){0.f, 0.f, 0.f, 0.f};

    bf16x8 bb[PF][2], aa[PF][4];
#pragma unroll
    for (int s = 0; s < PF; ++s) {
#pragma unroll
        for (int g = 0; g < 2; ++g)
            bb[s][g] = *reinterpret_cast<const bf16x8*>(
                xTb + (uint32_t)so[(g * 16 + l15) * K_TAPS + s] + qoff);
#pragma unroll
        for (int m = 0; m < 4; ++m)
            aa[s][m] = *reinterpret_cast<const bf16x8*>(aB + ((size_t)(s * 4 + m) << 10));
    }

#pragma unroll 3
    for (int k = 0; k < K_TAPS; ++k) {
        int cur = k % PF;
#pragma unroll
        for (int m = 0; m < 4; ++m)
#pragma unroll
            for (int g = 0; g < 2; ++g)
                acc[m][g] = __builtin_amdgcn_mfma_f32_16x16x32_bf16(
                    aa[cur][m], bb[cur][g], acc[m][g], 0, 0, 0);
        if (k < K_TAPS - PF) {
            int kn = k + PF;
#pragma unroll
            for (int g = 0; g < 2; ++g)
                bb[cur][g] = *reinterpret_cast<const bf16x8*>(
                    xTb + (uint32_t)so[(g * 16 + l15) * K_TAPS + kn] + qoff);
#pragma unroll
            for (int m = 0; m < 4; ++m)
                aa[cur][m] = *reinterpret_cast<const bf16x8*>(
                    aB + ((size_t)(kn * 4 + m) << 10));
        }
    }

    // store y tile (C/D: col=l15 -> node, row=quad*4+r -> channel)
#pragma unroll
    for (int m = 0; m < 4; ++m) {
        int obase = m * 16 + quad * 4;
#pragma unroll
        for (int g = 0; g < 2; ++g) {
            int n = nb + g * 16 + l15;
            if (n < N_NODES) {
#pragma unroll
                for (int r = 0; r < 4; ++r)
                    y[(size_t)(obase + r) * N_NODES + n] = acc[m][g][r];
            }
        }
    }

    // per-channel partial sums, striped over NSLOTS buffers
    int slot = blockIdx.x & (NSLOTS - 1);
#pragma unroll
    for (int m = 0; m < 4; ++m) {
#pragma unroll
        for (int r = 0; r < 4; ++r) {
            float s = 0.f, sq = 0.f;
#pragma unroll
            for (int g = 0; g < 2; ++g) {
                float v = acc[m][g][r];
                s += v;
                sq += v * v;
            }
#pragma unroll
            for (int d = 1; d < 16; d <<= 1) {
                s += __shfl_xor(s, d);
                sq += __shfl_xor(sq, d);
            }
            if (l15 == 0) {
                int o = m * 16 + quad * 4 + r;
                atomicAdd(&stats[slot * 128 + o], s);
                atomicAdd(&stats[slot * 128 + 64 + o], sq);
            }
        }
    }
}

// ---------------------------------------------------------------------------
// Kernel 3: finalize stats (per block, cheap) + in-place BN + ReLU on y.
// Grid: (37, 64); each block: 1024 float4 = 4096 floats of one channel.
// ---------------------------------------------------------------------------
__global__ __launch_bounds__(256) void k_bn_relu(float* __restrict__ y,
                                                 const float* __restrict__ stats,
                                                 const float* __restrict__ gamma,
                                                 const float* __restrict__ beta) {
    __shared__ float s_sc, s_sh;
    int t = threadIdx.x;
    int o = blockIdx.y;
    if (t < 32) {
        float s = stats[t * 128 + o];
        float sq = stats[t * 128 + 64 + o];
#pragma unroll
        for (int d = 1; d < 32; d <<= 1) {
            s += __shfl_xor(s, d);
            sq += __shfl_xor(sq, d);
        }
        if (t == 0) {
            const float invN = 1.0f / (float)N_NODES;
            float mean = s * invN;
            float var = sq * invN - mean * mean;
            float rstd = rsqrtf(var + 1e-3f);
            float sc = gamma[o] * rstd;
            s_sc = sc;
            s_sh = beta[o] - mean * sc;
        }
    }
    __syncthreads();
    float sc = s_sc, sh = s_sh;
    float4* row = reinterpret_cast<float4*>(y + (size_t)o * N_NODES);
    int base = blockIdx.x * 1024 + t;
#pragma unroll
    for (int it = 0; it < 4; ++it) {
        int i = base + it * 256;
        if (i < N_NODES / 4) {
            float4 v = row[i];
            v.x = fmaxf(fmaf(v.x, sc, sh), 0.f);
            v.y = fmaxf(fmaf(v.y, sc, sh), 0.f);
            v.z = fmaxf(fmaf(v.z, sc, sh), 0.f);
            v.w = fmaxf(fmaf(v.w, sc, sh), 0.f);
            row[i] = v;
        }
    }
}

extern "C" void kernel_launch(void* const* d_in, const int* in_sizes, int n_in,
                              void* d_out, int out_size, void* d_ws, size_t ws_size,
                              hipStream_t stream) {
    const float* data_in = (const float*)d_in[0];
    const int* neigh = (const int*)d_in[1];
    const float* W = (const float*)d_in[2];
    const float* gamma = (const float*)d_in[3];
    const float* beta = (const float*)d_in[4];
    float* out = (float*)d_out;

    char* ws = (char*)d_ws;
    ushort* xT = (ushort*)ws;                     // 150016*32*2 = 9,601,024 B
    ushort* A_frag = (ushort*)(ws + 9601024);     // 64*864*2    =   110,592 B
    float* stats = (float*)(ws + 9711616);        // 32*128 partials (+pad)

    k_prep<<<TRANS_BLOCKS + WPREP_BLOCKS, 256, 0, stream>>>(data_in, xT, W, A_frag,
                                                            stats);
    k_conv<<<CONV_BLOCKS, 128, 0, stream>>>(xT, A_frag, neigh, out, stats);
    k_bn_relu<<<dim3((N_NODES / 4 + 1023) / 1024, C_OUT), 256, 0, stream>>>(
        out, stats, gamma, beta);
}

// Round 5
// 174.937 us; speedup vs baseline: 1.7824x; 1.0244x over previous
//
#include <hip/hip_runtime.h>
#include <hip/hip_bf16.h>
#include <stdint.h>

#define N_NODES 150000
#define C_IN 32
#define C_OUT 64
#define K_TAPS 27
#define K_PAD 28                    // taps padded to 28 (tap 27 = zero weights, pad-row gather)
#define PF 3
#define NSTEP 7                     // 28 / 4 waves
#define NSLOTS 32

#define TRANS_BLOCKS 2344           // 2344*64 = 150016 nodes (incl. pad row)
#define WPREP_BLOCKS 224            // 224*256 >= 64*32*28 = 57344
#define CONV_BLOCKS 4688            // 4688*32 = 150016 nodes, 4 waves/block (K-split)

typedef __attribute__((ext_vector_type(8))) __bf16 bf16x8;
typedef __attribute__((ext_vector_type(4))) float f32x4;

__device__ __forceinline__ ushort f2bf(float f) {
    union { float f; uint32_t u; } v; v.f = f;
    uint32_t u = v.u;
    return (ushort)((u + 0x7FFFu + ((u >> 16) & 1u)) >> 16);
}

// ---------------------------------------------------------------------------
// Kernel 1 (fused prep): blocks [0,2344) transpose x (32x150000 fp32) ->
// xT (150001 x 32 bf16, zero pad row). Blocks [2344,2568) repack W (28 taps,
// tap 27 zeroed) and zero stats.
// ---------------------------------------------------------------------------
__global__ __launch_bounds__(256) void k_prep(const float* __restrict__ x,
                                              ushort* __restrict__ xT,
                                              const float* __restrict__ W,
                                              ushort* __restrict__ A_frag,
                                              float* __restrict__ stats) {
    int t = threadIdx.x;
    int b = blockIdx.x;
    if (b < TRANS_BLOCKS) {
        __shared__ float tile[32][65];
        int nb = b * 64;
        int nl = t & 63, i4 = t >> 6;
#pragma unroll
        for (int rep = 0; rep < 8; ++rep) {
            int i = rep * 4 + i4;
            int n = nb + nl;
            tile[i][nl] = (n < N_NODES) ? x[(size_t)i * N_NODES + n] : 0.0f;
        }
        __syncthreads();
        int nr = t >> 2, c0 = (t & 3) * 8;
        int n = nb + nr;
        if (n <= N_NODES) {
            uint32_t w[4];
#pragma unroll
            for (int j = 0; j < 4; ++j) {
                ushort lo = f2bf(tile[c0 + 2 * j][nr]);
                ushort hi = f2bf(tile[c0 + 2 * j + 1][nr]);
                w[j] = (uint32_t)lo | ((uint32_t)hi << 16);
            }
            *reinterpret_cast<uint4*>(xT + (size_t)n * 32 + c0) =
                make_uint4(w[0], w[1], w[2], w[3]);
        }
    } else {
        // A_frag[(k*4+m)*512 + lane*8 + j] = W[m*16+(lane&15)][(lane>>4)*8+j][k]
        int tid = (b - TRANS_BLOCKS) * 256 + t;
        if (tid < NSLOTS * 128 + 128) stats[tid] = 0.0f;
        if (tid < C_OUT * C_IN * K_PAD) {
            int j = tid & 7;
            int ln = (tid >> 3) & 63;
            int km = tid >> 9;
            int m = km & 3;
            int k = km >> 2;
            int o = m * 16 + (ln & 15);
            int i = (ln >> 4) * 8 + j;
            A_frag[tid] =
                (k < K_TAPS) ? f2bf(W[o * (C_IN * K_TAPS) + i * K_TAPS + k]) : (ushort)0;
        }
    }
}

// ---------------------------------------------------------------------------
// Kernel 2: gather-GEMM, K-split over 4 waves. Block = 256 thr = 4 waves,
// 32 nodes/block; wave w handles taps {w, w+4, ..., w+24} (tap 27 is zero-pad).
// Each wave keeps the round-2 PF=3 register pipeline verbatim (VGPR ~60).
// Partials combined via LDS; coalesced cooperative y store; wave0 does stats.
// ---------------------------------------------------------------------------
__global__ __launch_bounds__(256, 4) void k_conv(const ushort* __restrict__ xT,
                                                 const ushort* __restrict__ A_frag,
                                                 const int* __restrict__ neigh,
                                                 float* __restrict__ y,
                                                 float* __restrict__ stats) {
    __shared__ int soff[32 * K_PAD];   // [node][28] pre-scaled byte offsets
    __shared__ float sacc[C_OUT * 32]; // [o][n] summed partials
    int t = threadIdx.x;
    int nb = blockIdx.x * 32;
    for (int j = t; j < 32 * K_PAD; j += 256) {
        int n = j / K_PAD;
        int kk = j - n * K_PAD;
        int ng = nb + n;
        int idx = (kk < K_TAPS && ng < N_NODES) ? neigh[(size_t)ng * K_TAPS + kk]
                                                : N_NODES;
        soff[j] = idx << 6;  // 64 B per xT row
    }
    __syncthreads();

    int wid = t >> 6, lane = t & 63;
    int l15 = lane & 15, quad = lane >> 4;
    int qoff = quad << 4;

    const char* xTb = (const char*)xT;
    const char* aB = (const char*)A_frag + (size_t)lane * 16;

    f32x4 acc[4][2];
#pragma unroll
    for (int m = 0; m < 4; ++m)
#pragma unroll
        for (int g = 0; g < 2; ++g) acc[m][g] = (f32x4){0.f, 0.f, 0.f, 0.f};

    bf16x8 bb[PF][2], aa[PF][4];
#pragma unroll
    for (int s = 0; s < PF; ++s) {
        int k = wid + 4 * s;
#pragma unroll
        for (int g = 0; g < 2; ++g)
            bb[s][g] = *reinterpret_cast<const bf16x8*>(
                xTb + (uint32_t)soff[(g * 16 + l15) * K_PAD + k] + qoff);
#pragma unroll
        for (int m = 0; m < 4; ++m)
            aa[s][m] = *reinterpret_cast<const bf16x8*>(aB + ((size_t)(k * 4 + m) << 10));
    }

#pragma unroll
    for (int s = 0; s < NSTEP; ++s) {
        int cur = s % PF;
#pragma unroll
        for (int m = 0; m < 4; ++m)
#pragma unroll
            for (int g = 0; g < 2; ++g)
                acc[m][g] = __builtin_amdgcn_mfma_f32_16x16x32_bf16(
                    aa[cur][m], bb[cur][g], acc[m][g], 0, 0, 0);
        if (s < NSTEP - PF) {
            int kn = wid + 4 * (s + PF);
#pragma unroll
            for (int g = 0; g < 2; ++g)
                bb[cur][g] = *reinterpret_cast<const bf16x8*>(
                    xTb + (uint32_t)soff[(g * 16 + l15) * K_PAD + kn] + qoff);
#pragma unroll
            for (int m = 0; m < 4; ++m)
                aa[cur][m] = *reinterpret_cast<const bf16x8*>(
                    aB + ((size_t)(kn * 4 + m) << 10));
        }
    }

    // combine partials: wave0 writes, waves 1..3 add in place (C/D layout:
    // col=l15+g*16 -> node, row=quad*4+r (+16m) -> channel)
    if (wid == 0) {
#pragma unroll
        for (int m = 0; m < 4; ++m)
#pragma unroll
            for (int g = 0; g < 2; ++g)
#pragma unroll
                for (int r = 0; r < 4; ++r)
                    sacc[(m * 16 + quad * 4 + r) * 32 + g * 16 + l15] = acc[m][g][r];
    }
    __syncthreads();
#pragma unroll
    for (int w = 1; w < 4; ++w) {
        if (wid == w) {
#pragma unroll
            for (int m = 0; m < 4; ++m)
#pragma unroll
                for (int g = 0; g < 2; ++g)
#pragma unroll
                    for (int r = 0; r < 4; ++r)
                        sacc[(m * 16 + quad * 4 + r) * 32 + g * 16 + l15] +=
                            acc[m][g][r];
        }
        __syncthreads();
    }

    // cooperative coalesced y store: 2048 floats, 8 per thread
#pragma unroll
    for (int rep = 0; rep < 8; ++rep) {
        int idx = rep * 256 + t;
        int o = idx >> 5;
        int n = nb + (idx & 31);
        if (n < N_NODES) y[(size_t)o * N_NODES + n] = sacc[idx];
    }

    // stats from summed buffer (wave0 only), striped over NSLOTS buffers
    if (wid == 0) {
        int slot = blockIdx.x & (NSLOTS - 1);
#pragma unroll
        for (int m = 0; m < 4; ++m) {
#pragma unroll
            for (int r = 0; r < 4; ++r) {
                int o = m * 16 + quad * 4 + r;
                float s = 0.f, sq = 0.f;
#pragma unroll
                for (int g = 0; g < 2; ++g) {
                    float v = sacc[o * 32 + g * 16 + l15];
                    s += v;
                    sq += v * v;
                }
#pragma unroll
                for (int d = 1; d < 16; d <<= 1) {
                    s += __shfl_xor(s, d);
                    sq += __shfl_xor(sq, d);
                }
                if (l15 == 0) {
                    atomicAdd(&stats[slot * 128 + o], s);
                    atomicAdd(&stats[slot * 128 + 64 + o], sq);
                }
            }
        }
    }
}

// ---------------------------------------------------------------------------
// Kernel 3: finalize stats (per block, cheap) + in-place BN + ReLU on y.
// Grid: (37, 64); each block: 1024 float4 = 4096 floats of one channel.
// ---------------------------------------------------------------------------
__global__ __launch_bounds__(256) void k_bn_relu(float* __restrict__ y,
                                                 const float* __restrict__ stats,
                                                 const float* __restrict__ gamma,
                                                 const float* __restrict__ beta) {
    __shared__ float s_sc, s_sh;
    int t = threadIdx.x;
    int o = blockIdx.y;
    if (t < 32) {
        float s = stats[t * 128 + o];
        float sq = stats[t * 128 + 64 + o];
#pragma unroll
        for (int d = 1; d < 32; d <<= 1) {
            s += __shfl_xor(s, d);
            sq += __shfl_xor(sq, d);
        }
        if (t == 0) {
            const float invN = 1.0f / (float)N_NODES;
            float mean = s * invN;
            float var = sq * invN - mean * mean;
            float rstd = rsqrtf(var + 1e-3f);
            float sc = gamma[o] * rstd;
            s_sc = sc;
            s_sh = beta[o] - mean * sc;
        }
    }
    __syncthreads();
    float sc = s_sc, sh = s_sh;
    float4* row = reinterpret_cast<float4*>(y + (size_t)o * N_NODES);
    int base = blockIdx.x * 1024 + t;
#pragma unroll
    for (int it = 0; it < 4; ++it) {
        int i = base + it * 256;
        if (i < N_NODES / 4) {
            float4 v = row[i];
            v.x = fmaxf(fmaf(v.x, sc, sh), 0.f);
            v.y = fmaxf(fmaf(v.y, sc, sh), 0.f);
            v.z = fmaxf(fmaf(v.z, sc, sh), 0.f);
            v.w = fmaxf(fmaf(v.w, sc, sh), 0.f);
            row[i] = v;
        }
    }
}

extern "C" void kernel_launch(void* const* d_in, const int* in_sizes, int n_in,
                              void* d_out, int out_size, void* d_ws, size_t ws_size,
                              hipStream_t stream) {
    const float* data_in = (const float*)d_in[0];
    const int* neigh = (const int*)d_in[1];
    const float* W = (const float*)d_in[2];
    const float* gamma = (const float*)d_in[3];
    const float* beta = (const float*)d_in[4];
    float* out = (float*)d_out;

    char* ws = (char*)d_ws;
    ushort* xT = (ushort*)ws;                     // 150016*32*2 = 9,601,024 B
    ushort* A_frag = (ushort*)(ws + 9601024);     // 64*32*28*2  =   114,688 B
    float* stats = (float*)(ws + 9715712);        // 32*128 partials (+pad)

    k_prep<<<TRANS_BLOCKS + WPREP_BLOCKS, 256, 0, stream>>>(data_in, xT, W, A_frag,
                                                            stats);
    k_conv<<<CONV_BLOCKS, 256, 0, stream>>>(xT, A_frag, neigh, out, stats);
    k_bn_relu<<<dim3((N_NODES / 4 + 1023) / 1024, C_OUT), 256, 0, stream>>>(
        out, stats, gamma, beta);
}

// Round 6
// 171.606 us; speedup vs baseline: 1.8170x; 1.0194x over previous
//
#include <hip/hip_runtime.h>
#include <hip/hip_bf16.h>
#include <stdint.h>

#define N_NODES 150000
#define C_IN 32
#define C_OUT 64
#define K_TAPS 27
#define K_PAD 28                    // taps padded to 28 (tap 27 = zero weights, pad-row gather)
#define PF 3
#define NSTEP 7                     // 28 / 4 waves
#define NSLOTS 32
#define Y_STRIDE 150016             // bf16 y row stride (keeps 16B alignment)

#define TRANS_BLOCKS 2344           // 2344*64 = 150016 nodes (incl. pad row)
#define WPREP_BLOCKS 224            // 224*256 >= 64*32*28 = 57344
#define CONV_BLOCKS 4688            // 4688*32 = 150016 nodes, 4 waves/block (K-split)
#define WS_NEED 28934656ull         // xT + A_frag + stats + yb

typedef __attribute__((ext_vector_type(8))) __bf16 bf16x8;
typedef __attribute__((ext_vector_type(4))) float f32x4;
typedef __attribute__((ext_vector_type(4))) uint32_t u32x4;

__device__ __forceinline__ ushort f2bf(float f) {
    union { float f; uint32_t u; } v; v.f = f;
    uint32_t u = v.u;
    return (ushort)((u + 0x7FFFu + ((u >> 16) & 1u)) >> 16);
}

// ---------------------------------------------------------------------------
// Kernel 1 (fused prep): blocks [0,2344) transpose x (32x150000 fp32) ->
// xT (150001 x 32 bf16, zero pad row). Blocks [2344,2568) repack W (28 taps,
// tap 27 zeroed) and zero stats.
// ---------------------------------------------------------------------------
__global__ __launch_bounds__(256) void k_prep(const float* __restrict__ x,
                                              ushort* __restrict__ xT,
                                              const float* __restrict__ W,
                                              ushort* __restrict__ A_frag,
                                              float* __restrict__ stats) {
    int t = threadIdx.x;
    int b = blockIdx.x;
    if (b < TRANS_BLOCKS) {
        __shared__ float tile[32][65];
        int nb = b * 64;
        int nl = t & 63, i4 = t >> 6;
#pragma unroll
        for (int rep = 0; rep < 8; ++rep) {
            int i = rep * 4 + i4;
            int n = nb + nl;
            tile[i][nl] = (n < N_NODES) ? x[(size_t)i * N_NODES + n] : 0.0f;
        }
        __syncthreads();
        int nr = t >> 2, c0 = (t & 3) * 8;
        int n = nb + nr;
        if (n <= N_NODES) {
            uint32_t w[4];
#pragma unroll
            for (int j = 0; j < 4; ++j) {
                ushort lo = f2bf(tile[c0 + 2 * j][nr]);
                ushort hi = f2bf(tile[c0 + 2 * j + 1][nr]);
                w[j] = (uint32_t)lo | ((uint32_t)hi << 16);
            }
            *reinterpret_cast<uint4*>(xT + (size_t)n * 32 + c0) =
                make_uint4(w[0], w[1], w[2], w[3]);
        }
    } else {
        // A_frag[(k*4+m)*512 + lane*8 + j] = W[m*16+(lane&15)][(lane>>4)*8+j][k]
        int tid = (b - TRANS_BLOCKS) * 256 + t;
        if (tid < NSLOTS * 128 + 128) stats[tid] = 0.0f;
        if (tid < C_OUT * C_IN * K_PAD) {
            int j = tid & 7;
            int ln = (tid >> 3) & 63;
            int km = tid >> 9;
            int m = km & 3;
            int k = km >> 2;
            int o = m * 16 + (ln & 15);
            int i = (ln >> 4) * 8 + j;
            A_frag[tid] =
                (k < K_TAPS) ? f2bf(W[o * (C_IN * K_TAPS) + i * K_TAPS + k]) : (ushort)0;
        }
    }
}

// ---------------------------------------------------------------------------
// Kernel 2: gather-GEMM, K-split over 4 waves (unchanged hot loop).
// New: y stored NON-TEMPORALLY (no L2 allocate -> protect xT residency),
// as bf16 into ws (use_bf16=1) or fp32 into d_out (fallback).
// ---------------------------------------------------------------------------
__global__ __launch_bounds__(256, 4) void k_conv(const ushort* __restrict__ xT,
                                                 const ushort* __restrict__ A_frag,
                                                 const int* __restrict__ neigh,
                                                 float* __restrict__ yf,
                                                 ushort* __restrict__ yb,
                                                 float* __restrict__ stats,
                                                 int use_bf16) {
    __shared__ int soff[32 * K_PAD];   // [node][28] pre-scaled byte offsets
    __shared__ float sacc[C_OUT * 32]; // [o][n] summed partials
    int t = threadIdx.x;
    int nb = blockIdx.x * 32;
    for (int j = t; j < 32 * K_PAD; j += 256) {
        int n = j / K_PAD;
        int kk = j - n * K_PAD;
        int ng = nb + n;
        int idx = (kk < K_TAPS && ng < N_NODES) ? neigh[(size_t)ng * K_TAPS + kk]
                                                : N_NODES;
        soff[j] = idx << 6;  // 64 B per xT row
    }
    __syncthreads();

    int wid = t >> 6, lane = t & 63;
    int l15 = lane & 15, quad = lane >> 4;
    int qoff = quad << 4;

    const char* xTb = (const char*)xT;
    const char* aB = (const char*)A_frag + (size_t)lane * 16;

    f32x4 acc[4][2];
#pragma unroll
    for (int m = 0; m < 4; ++m)
#pragma unroll
        for (int g = 0; g < 2; ++g) acc[m][g] = (f32x4){0.f, 0.f, 0.f, 0.f};

    bf16x8 bb[PF][2], aa[PF][4];
#pragma unroll
    for (int s = 0; s < PF; ++s) {
        int k = wid + 4 * s;
#pragma unroll
        for (int g = 0; g < 2; ++g)
            bb[s][g] = *reinterpret_cast<const bf16x8*>(
                xTb + (uint32_t)soff[(g * 16 + l15) * K_PAD + k] + qoff);
#pragma unroll
        for (int m = 0; m < 4; ++m)
            aa[s][m] = *reinterpret_cast<const bf16x8*>(aB + ((size_t)(k * 4 + m) << 10));
    }

#pragma unroll
    for (int s = 0; s < NSTEP; ++s) {
        int cur = s % PF;
#pragma unroll
        for (int m = 0; m < 4; ++m)
#pragma unroll
            for (int g = 0; g < 2; ++g)
                acc[m][g] = __builtin_amdgcn_mfma_f32_16x16x32_bf16(
                    aa[cur][m], bb[cur][g], acc[m][g], 0, 0, 0);
        if (s < NSTEP - PF) {
            int kn = wid + 4 * (s + PF);
#pragma unroll
            for (int g = 0; g < 2; ++g)
                bb[cur][g] = *reinterpret_cast<const bf16x8*>(
                    xTb + (uint32_t)soff[(g * 16 + l15) * K_PAD + kn] + qoff);
#pragma unroll
            for (int m = 0; m < 4; ++m)
                aa[cur][m] = *reinterpret_cast<const bf16x8*>(
                    aB + ((size_t)(kn * 4 + m) << 10));
        }
    }

    // combine partials: wave0 writes, waves 1..3 add in place
    if (wid == 0) {
#pragma unroll
        for (int m = 0; m < 4; ++m)
#pragma unroll
            for (int g = 0; g < 2; ++g)
#pragma unroll
                for (int r = 0; r < 4; ++r)
                    sacc[(m * 16 + quad * 4 + r) * 32 + g * 16 + l15] = acc[m][g][r];
    }
    __syncthreads();
#pragma unroll
    for (int w = 1; w < 4; ++w) {
        if (wid == w) {
#pragma unroll
            for (int m = 0; m < 4; ++m)
#pragma unroll
                for (int g = 0; g < 2; ++g)
#pragma unroll
                    for (int r = 0; r < 4; ++r)
                        sacc[(m * 16 + quad * 4 + r) * 32 + g * 16 + l15] +=
                            acc[m][g][r];
        }
        __syncthreads();
    }

    // cooperative y store (non-temporal)
    if (use_bf16) {
        // thread t handles 8 consecutive elements of flattened [o][n32]
        int e0 = t * 8;
        int o = t >> 2;
        int n0 = (t & 3) * 8;
        uint32_t w[4];
#pragma unroll
        for (int j = 0; j < 4; ++j) {
            ushort lo = f2bf(sacc[e0 + 2 * j]);
            ushort hi = f2bf(sacc[e0 + 2 * j + 1]);
            w[j] = (uint32_t)lo | ((uint32_t)hi << 16);
        }
        u32x4 v = {w[0], w[1], w[2], w[3]};
        __builtin_nontemporal_store(
            v, reinterpret_cast<u32x4*>(yb + (size_t)o * Y_STRIDE + nb + n0));
    } else {
#pragma unroll
        for (int rep = 0; rep < 8; ++rep) {
            int idx = rep * 256 + t;
            int o = idx >> 5;
            int n = nb + (idx & 31);
            if (n < N_NODES)
                __builtin_nontemporal_store(sacc[idx], &yf[(size_t)o * N_NODES + n]);
        }
    }

    // stats from summed buffer (wave0 only); padding nodes contribute exact 0
    if (wid == 0) {
        int slot = blockIdx.x & (NSLOTS - 1);
#pragma unroll
        for (int m = 0; m < 4; ++m) {
#pragma unroll
            for (int r = 0; r < 4; ++r) {
                int o = m * 16 + quad * 4 + r;
                float s = 0.f, sq = 0.f;
#pragma unroll
                for (int g = 0; g < 2; ++g) {
                    float v = sacc[o * 32 + g * 16 + l15];
                    s += v;
                    sq += v * v;
                }
#pragma unroll
                for (int d = 1; d < 16; d <<= 1) {
                    s += __shfl_xor(s, d);
                    sq += __shfl_xor(sq, d);
                }
                if (l15 == 0) {
                    atomicAdd(&stats[slot * 128 + o], s);
                    atomicAdd(&stats[slot * 128 + 64 + o], sq);
                }
            }
        }
    }
}

// ---------------------------------------------------------------------------
// Kernel 3: finalize stats + BN + ReLU. Grid (37, 64).
// bf16 path: stream yb (nt loads) -> fp32 d_out (nt stores).
// fp32 path: in-place on d_out.
// ---------------------------------------------------------------------------
__global__ __launch_bounds__(256) void k_bn_relu(const ushort* __restrict__ yb,
                                                 float* __restrict__ out,
                                                 const float* __restrict__ stats,
                                                 const float* __restrict__ gamma,
                                                 const float* __restrict__ beta,
                                                 int use_bf16) {
    __shared__ float s_sc, s_sh;
    int t = threadIdx.x;
    int o = blockIdx.y;
    if (t < 32) {
        float s = stats[t * 128 + o];
        float sq = stats[t * 128 + 64 + o];
#pragma unroll
        for (int d = 1; d < 32; d <<= 1) {
            s += __shfl_xor(s, d);
            sq += __shfl_xor(sq, d);
        }
        if (t == 0) {
            const float invN = 1.0f / (float)N_NODES;
            float mean = s * invN;
            float var = sq * invN - mean * mean;
            float rstd = rsqrtf(var + 1e-3f);
            float sc = gamma[o] * rstd;
            s_sc = sc;
            s_sh = beta[o] - mean * sc;
        }
    }
    __syncthreads();
    float sc = s_sc, sh = s_sh;
    if (use_bf16) {
        const u32x4* row = reinterpret_cast<const u32x4*>(yb + (size_t)o * Y_STRIDE);
        f32x4* orow = reinterpret_cast<f32x4*>(out + (size_t)o * N_NODES);
#pragma unroll
        for (int it = 0; it < 2; ++it) {
            int c = blockIdx.x * 512 + it * 256 + t;  // chunk of 8 elements
            if (c < N_NODES / 8) {
                u32x4 v = __builtin_nontemporal_load(row + c);
                f32x4 f0, f1;
#pragma unroll
                for (int j = 0; j < 2; ++j) {
                    f0[2 * j] = __uint_as_float(v[j] << 16);
                    f0[2 * j + 1] = __uint_as_float(v[j] & 0xffff0000u);
                    f1[2 * j] = __uint_as_float(v[j + 2] << 16);
                    f1[2 * j + 1] = __uint_as_float(v[j + 2] & 0xffff0000u);
                }
#pragma unroll
                for (int j = 0; j < 4; ++j) {
                    f0[j] = fmaxf(fmaf(f0[j], sc, sh), 0.f);
                    f1[j] = fmaxf(fmaf(f1[j], sc, sh), 0.f);
                }
                __builtin_nontemporal_store(f0, orow + 2 * c);
                __builtin_nontemporal_store(f1, orow + 2 * c + 1);
            }
        }
    } else {
        float4* row = reinterpret_cast<float4*>(out + (size_t)o * N_NODES);
        int base = blockIdx.x * 1024 + t;
#pragma unroll
        for (int it = 0; it < 4; ++it) {
            int i = base + it * 256;
            if (i < N_NODES / 4) {
                float4 v = row[i];
                v.x = fmaxf(fmaf(v.x, sc, sh), 0.f);
                v.y = fmaxf(fmaf(v.y, sc, sh), 0.f);
                v.z = fmaxf(fmaf(v.z, sc, sh), 0.f);
                v.w = fmaxf(fmaf(v.w, sc, sh), 0.f);
                row[i] = v;
            }
        }
    }
}

extern "C" void kernel_launch(void* const* d_in, const int* in_sizes, int n_in,
                              void* d_out, int out_size, void* d_ws, size_t ws_size,
                              hipStream_t stream) {
    const float* data_in = (const float*)d_in[0];
    const int* neigh = (const int*)d_in[1];
    const float* W = (const float*)d_in[2];
    const float* gamma = (const float*)d_in[3];
    const float* beta = (const float*)d_in[4];
    float* out = (float*)d_out;

    char* ws = (char*)d_ws;
    ushort* xT = (ushort*)ws;                     // 150016*32*2 = 9,601,024 B
    ushort* A_frag = (ushort*)(ws + 9601024);     // 64*32*28*2  =   114,688 B
    float* stats = (float*)(ws + 9715712);        // 32*128 partials (+pad) = 16,896 B
    ushort* yb = (ushort*)(ws + 9732608);         // 64*150016*2 = 19,202,048 B

    int use_bf16 = (ws_size >= WS_NEED) ? 1 : 0;

    k_prep<<<TRANS_BLOCKS + WPREP_BLOCKS, 256, 0, stream>>>(data_in, xT, W, A_frag,
                                                            stats);
    k_conv<<<CONV_BLOCKS, 256, 0, stream>>>(xT, A_frag, neigh, out, yb, stats,
                                            use_bf16);
    k_bn_relu<<<dim3(37, C_OUT), 256, 0, stream>>>(yb, out, stats, gamma, beta,
                                                   use_bf16);
}